// Round 5
// baseline (361.613 us; speedup 1.0000x reference)
//
#include <hip/hip_runtime.h>
#include <math.h>

// DiceLoss fused kernel for MI355X — round 5: register-lean phase B to lift
// the VGPR-driven occupancy cap.
// B=32, C=1, H=W=1024 fp32. loss = mean_b(1 - (2*I_b + 1e-3)/(M_b + 1e-3))
//   I_b = sum sigmoid(o)*t*w,  M_b = sum (t+sigmoid(o))*w,
//   w = 1 + 5*|boxavg31(t) - t|, zero-padded, always /961.
//
// History:
// R1: FETCH=268MB minimal, latency-bound, 159us @ 43% occupancy.
// R2: reg prefetch: 141us. R3: bounds(256,8) forced VGPR 32 -> w[40]
//     spilled (WRITE 70MB) -> 208us. R4: YS=64 grid + bounds(256,4):
//     occupancy STILL 43% -> VGPR=60 itself is the cap.
// Empirical rule (R1-R4): waves/SIMD = floor(256/VGPR). 60->4 waves (43%),
//     32->8 waves (86%). Effective pool 256 VGPR/SIMD, compiler budget 256/N.
// R5: bounds(256,6) (budget 42) + strip-4 phase B: live window = 7 regs
//     (w0..w2, w31..w33, s; middle taps folded into s from load temps and
//     discarded), t/o center loads inside the strip loop, no cross-batch
//     prefetch. Target: no spill at 6 waves/SIMD = 75% occupancy.

namespace {
constexpr int Bn = 32;
constexpr int Hn = 1024;
constexpr int Wn = 1024;
constexpr int Rn = 15;           // kernel radius (K=31)
constexpr int TX = 256;          // tile width in outputs
constexpr int YS = 64;           // tile height in outputs
constexpr int NB = YS / 8;       // 8-row batches per tile
constexpr int NCOL = TX + 32;    // staged columns (halo 30 -> 32)
constexpr int PHYSW = (NCOL / 8) * 12;   // 432 floats per padded LDS row
constexpr float INV_KK = 1.0f / 961.0f;
}

__device__ __forceinline__ int phys(int i) { return i + ((i >> 3) << 2); }

__device__ __forceinline__ float ldcol(const float* p, int y, int col, bool xok) {
    return (xok && (unsigned)y < (unsigned)Hn) ? p[(size_t)y * Wn + col] : 0.0f;
}

__global__ __launch_bounds__(256, 6)
void dice_main(const float* __restrict__ logits, const float* __restrict__ tgt,
               float* __restrict__ acc)
{
    __shared__ __align__(16) float vbuf[8 * PHYSW];
    __shared__ float red[8];

    const int bid = blockIdx.x;
    const int b   = bid >> 6;          // 64 tiles per batch image
    const int rem = bid & 63;
    const int x0  = (rem >> 4) * TX;   // 4 x-tiles
    const int y0  = (rem & 15) * YS;   // 16 y-tiles
    const int t   = threadIdx.x;

    const float* tb = tgt    + (size_t)b * Hn * Wn;
    const float* ob = logits + (size_t)b * Hn * Wn;

    // Vertical-sum ownership: thread t owns staged col t; t<32 also 256+t.
    const int  col0 = x0 - Rn + t;            // in [x0-15, x0+240] -> only low guard
    const bool has2 = (t < 32);
    const int  col1 = col0 + 256;             // in [x0+241, x0+272] -> only high guard
    const bool xok0 = (col0 >= 0);
    const bool xok1 = (col1 < Wn);
    const int  pt   = phys(t);
    const int  pt2  = phys(256 + t);

    // Phase-B identity: 8 rows x 64 strips of 4; thread does items t and t+256
    // -> same strip jj, rows r0 and r0+4.
    const int r0 = t >> 6;             // 0..3
    const int jj = t & 63;             // strip index
    const int xb = x0 + (jj << 2);     // output col base (16B aligned)

    // ---- init vertical box sums for output row y0 ----
    float vs0 = 0.0f, vs1 = 0.0f;
    for (int yy = y0 - Rn; yy <= y0 + Rn; ++yy) {
        vs0 += ldcol(tb, yy, col0, xok0);
        if (has2) vs1 += ldcol(tb, yy, col1, xok1);
    }

    float acc_i = 0.0f, acc_m = 0.0f;

    for (int it = 0; it < NB; ++it) {
        const int ya = y0 + it * 8;

        // ---- phase A: advance vertical sums, stage 8 rows to LDS ----
        #pragma unroll
        for (int r = 0; r < 8; ++r) {
            const int yr = ya + r;
            if (it > 0 || r > 0) {
                vs0 += ldcol(tb, yr + Rn, col0, xok0) - ldcol(tb, yr - Rn - 1, col0, xok0);
                if (has2) vs1 += ldcol(tb, yr + Rn, col1, xok1) - ldcol(tb, yr - Rn - 1, col1, xok1);
            }
            vbuf[r * PHYSW + pt] = vs0;
            if (has2) vbuf[r * PHYSW + pt2] = vs1;
        }
        __syncthreads();

        // ---- phase B: two 4-wide strips, register-lean sliding window ----
        #pragma unroll
        for (int ss = 0; ss < 2; ++ss) {
            const int  row  = r0 + ss * 4;
            const int  yrow = ya + row;
            const float* vr = &vbuf[row * PHYSW];
            const int  base = jj << 2;

            const float4 tc4 = *(const float4*)(tb + (size_t)yrow * Wn + xb);
            const float4 oc4 = *(const float4*)(ob + (size_t)yrow * Wn + xb);

            // window taps w[d] = vr[base+d], d=0..33; keep only 7 live.
            const float4 a = *(const float4*)&vr[phys(base)];        // w0..w3
            float s = a.w;
            #pragma unroll
            for (int k = 1; k < 7; ++k) {                            // w4..w27
                const float4 q = *(const float4*)&vr[phys(base + 4 * k)];
                s += (q.x + q.y) + (q.z + q.w);
            }
            const float4 h = *(const float4*)&vr[phys(base + 28)];   // w28..w31
            s += (h.x + h.y) + h.z;
            const float4 g = *(const float4*)&vr[phys(base + 32)];   // w32..w35

            float sm = s + (a.x + a.y) + a.z;                        // sum w0..w30
            const float tcv[4]  = {tc4.x, tc4.y, tc4.z, tc4.w};
            const float ocv[4]  = {oc4.x, oc4.y, oc4.z, oc4.w};
            const float wsub[3] = {a.x, a.y, a.z};
            const float wadd[3] = {h.w, g.x, g.y};

            #pragma unroll
            for (int m = 0; m < 4; ++m) {
                if (m > 0) sm += wadd[m - 1] - wsub[m - 1];
                const float avg = sm * INV_KK;
                const float wt  = 1.0f + 5.0f * fabsf(avg - tcv[m]);
                const float sg  = 1.0f / (1.0f + __expf(-ocv[m]));
                acc_i += sg * tcv[m] * wt;
                acc_m += (tcv[m] + sg) * wt;
            }
        }
        __syncthreads();
    }

    // ---- block reduction ----
    #pragma unroll
    for (int off = 32; off > 0; off >>= 1) {
        acc_i += __shfl_down(acc_i, off);
        acc_m += __shfl_down(acc_m, off);
    }
    const int lane = t & 63;
    const int wv   = t >> 6;
    if (lane == 0) { red[wv * 2] = acc_i; red[wv * 2 + 1] = acc_m; }
    __syncthreads();
    if (t == 0) {
        atomicAdd(&acc[2 * b],     red[0] + red[2] + red[4] + red[6]);
        atomicAdd(&acc[2 * b + 1], red[1] + red[3] + red[5] + red[7]);
    }
}

__global__ void dice_final(const float* __restrict__ acc, float* __restrict__ out)
{
    const int t = threadIdx.x;
    float l = 0.0f;
    if (t < Bn) {
        const float I = acc[2 * t];
        const float M = acc[2 * t + 1];
        l = 1.0f - (2.0f * I + 0.001f) / (M + 0.001f);
    }
    #pragma unroll
    for (int off = 32; off > 0; off >>= 1) l += __shfl_down(l, off);
    if (t == 0) out[0] = l * (1.0f / 32.0f);
}

extern "C" void kernel_launch(void* const* d_in, const int* in_sizes, int n_in,
                              void* d_out, int out_size, void* d_ws, size_t ws_size,
                              hipStream_t stream)
{
    const float* logits = (const float*)d_in[0];   // "output" in reference
    const float* target = (const float*)d_in[1];
    float* acc = (float*)d_ws;                     // 64 floats: (I_b, M_b) per batch

    hipMemsetAsync(d_ws, 0, 64 * sizeof(float), stream);
    dice_main<<<dim3(Bn * 64), dim3(256), 0, stream>>>(logits, target, acc);
    dice_final<<<dim3(1), dim3(64), 0, stream>>>(acc, (float*)d_out);
}

// Round 6
// 319.039 us; speedup vs baseline: 1.1334x; 1.1334x over previous
//
#include <hip/hip_runtime.h>
#include <math.h>

// DiceLoss fused kernel for MI355X — round 6: wave-autonomous tiles, ZERO
// barriers in the hot loop.
// B=32, C=1, H=W=1024 fp32. loss = mean_b(1 - (2*I_b + 1e-3)/(M_b + 1e-3))
//   I_b = sum sigmoid(o)*t*w,  M_b = sum (t+sigmoid(o))*w,
//   w = 1 + 5*|boxavg31(t) - t|, zero-padded, always /961.
//
// History:
// R1 159us: barrier-phased block tiles, FETCH minimal 268MB, 1.7TB/s, latency-bound.
// R2 141us: +register prefetch — gain capped because the compiler emits
//    s_waitcnt vmcnt(0) before EVERY s_barrier: each batch drains the VMEM queue.
// R3 208us: bounds(256,8) -> VGPR 32, spilled (WRITE 70MB).
// R4 166us: YS=64 + bounds(256,4): occupancy stuck at 43% (VGPR=60 cap).
// R5 186us: reg-lean strip-4: VGPR 40 but occ only 48%, 2x LDS reads, more conflicts.
// Conclusion: stop chasing occupancy; remove the barriers instead.
//
// R6: each WAVE owns a 256x64 tile + a private 432-float LDS row buffer.
// Same-wave LDS write->read needs no __syncthreads (DS is in-order per wave).
// Explicit 1-row-ahead prefetch (add/sub rows + t/o centers) now survives —
// there is no barrier to drain it. 2048 waves / 512 blocks = 8 free-running
// waves/CU. Per-CU busy floor: VALU ~45us, HBM ~50us, overlapped.

namespace {
constexpr int Bn = 32;
constexpr int Hn = 1024;
constexpr int Wn = 1024;
constexpr int Rn = 15;            // kernel radius (K=31)
constexpr int XS = 256;           // per-wave strip width (outputs)
constexpr int YSW = 64;           // per-wave rows
constexpr int NCOL = XS + 32;     // 288 staged columns (30-halo -> 32)
constexpr int PHYSW = (NCOL / 8) * 12;   // 432 floats, pad 4 per 8
constexpr int WPB = 4;            // waves per block
constexpr float INV_KK = 1.0f / 961.0f;
}

__device__ __forceinline__ int phys(int i) { return i + ((i >> 3) << 2); }

__device__ __forceinline__ float ldc(const float* rowp, int c, bool ok) {
    return ok ? rowp[c] : 0.0f;
}

__global__ __launch_bounds__(256, 2)
void dice_main(const float* __restrict__ logits, const float* __restrict__ tgt,
               float* __restrict__ acc)
{
    __shared__ __align__(16) float vbuf[WPB][PHYSW];

    const int t   = threadIdx.x & 63;          // lane
    const int wid = threadIdx.x >> 6;          // wave in block
    const int gw  = blockIdx.x * WPB + wid;    // global wave id, 0..2047

    const int b   = gw >> 6;                   // 64 waves per image
    const int rem = gw & 63;
    const int x0  = (rem >> 4) * XS;           // 4 col-strips
    const int y0  = (rem & 15) * YSW;          // 16 row-tiles

    const float* tb = tgt    + (size_t)b * Hn * Wn;
    const float* ob = logits + (size_t)b * Hn * Wn;
    float* wb = vbuf[wid];

    // Staged columns: lane owns staged {t, 64+t, 128+t, 192+t} (+256+t if t<32).
    // Middle three are always in [49,1008] -> no x-guard.
    const int  c0   = x0 - Rn + t;
    const bool hasv4 = (t < 32);
    const int  c4   = x0 - Rn + 256 + t;
    const bool xok0 = (c0 >= 0);
    const bool xok4 = (c4 < Wn);

    // Phase-B strip: 4 outputs at cols x0+4t..x0+4t+3.
    const int xb   = x0 + (t << 2);
    const int base = t << 2;

    // ---- init vertical 31-sums for output row y0 ----
    float vs0 = 0.f, vs1 = 0.f, vs2 = 0.f, vs3 = 0.f, vs4 = 0.f;
    for (int yy = y0 - Rn; yy <= y0 + Rn; ++yy) {
        if ((unsigned)yy < (unsigned)Hn) {     // uniform branch
            const float* rp = tb + (size_t)yy * Wn;
            vs0 += ldc(rp, c0, xok0);
            vs1 += rp[c0 + 64];
            vs2 += rp[c0 + 128];
            vs3 += rp[c0 + 192];
            if (hasv4) vs4 += ldc(rp, c4, xok4);
        }
    }

    // ---- prefetch centers (row y0) and add/sub rows (for row y0+1) ----
    float4 ct = *(const float4*)(tb + (size_t)y0 * Wn + xb);
    float4 co = *(const float4*)(ob + (size_t)y0 * Wn + xb);

    float na0 = 0.f, na1 = 0.f, na2 = 0.f, na3 = 0.f, na4 = 0.f;
    float nu0 = 0.f, nu1 = 0.f, nu2 = 0.f, nu3 = 0.f, nu4 = 0.f;
    {
        const int ya = y0 + 1 + Rn, yu = y0 - Rn;   // sub row for y0+1 is y0-15
        if ((unsigned)ya < (unsigned)Hn) {
            const float* rp = tb + (size_t)ya * Wn;
            na0 = ldc(rp, c0, xok0); na1 = rp[c0 + 64];
            na2 = rp[c0 + 128];      na3 = rp[c0 + 192];
            if (hasv4) na4 = ldc(rp, c4, xok4);
        }
        if ((unsigned)yu < (unsigned)Hn) {
            const float* rp = tb + (size_t)yu * Wn;
            nu0 = ldc(rp, c0, xok0); nu1 = rp[c0 + 64];
            nu2 = rp[c0 + 128];      nu3 = rp[c0 + 192];
            if (hasv4) nu4 = ldc(rp, c4, xok4);
        }
    }

    float acc_i = 0.f, acc_m = 0.f;

    #pragma unroll 2
    for (int r = 0; r < YSW; ++r) {
        const int y = y0 + r;

        // stage current row's vertical sums to private LDS (no barrier)
        wb[phys(t)]        = vs0;
        wb[phys(64 + t)]   = vs1;
        wb[phys(128 + t)]  = vs2;
        wb[phys(192 + t)]  = vs3;
        if (hasv4) wb[phys(256 + t)] = vs4;

        // prefetch next-row centers
        float4 nt, no;
        if (r + 1 < YSW) {
            nt = *(const float4*)(tb + (size_t)(y + 1) * Wn + xb);
            no = *(const float4*)(ob + (size_t)(y + 1) * Wn + xb);
        }

        // horizontal 31-tap: 9 aligned b128 reads, lean register slide
        {
            const float4 A  = *(const float4*)&wb[phys(base)];        // w0..w3
            float mid = 0.f;
            #pragma unroll
            for (int k = 1; k < 7; ++k) {                             // w4..w27
                const float4 q = *(const float4*)&wb[phys(base + (k << 2))];
                mid += (q.x + q.y) + (q.z + q.w);
            }
            const float4 Hh = *(const float4*)&wb[phys(base + 28)];   // w28..w31
            const float4 G  = *(const float4*)&wb[phys(base + 32)];   // w32..w35

            float wsum = mid + (A.x + A.y) + (A.z + A.w)
                             + (Hh.x + Hh.y) + Hh.z;                  // w0..w30
            const float tcv[4]  = {ct.x, ct.y, ct.z, ct.w};
            const float ocv[4]  = {co.x, co.y, co.z, co.w};
            const float wsub[3] = {A.x, A.y, A.z};
            const float wadd[3] = {Hh.w, G.x, G.y};

            #pragma unroll
            for (int m = 0; m < 4; ++m) {
                if (m > 0) wsum += wadd[m - 1] - wsub[m - 1];
                const float avg = wsum * INV_KK;
                const float wt  = 1.0f + 5.0f * fabsf(avg - tcv[m]);
                const float sg  = 1.0f / (1.0f + __expf(-ocv[m]));
                acc_i += sg * tcv[m] * wt;
                acc_m += (tcv[m] + sg) * wt;
            }
        }

        // consume prefetched add/sub for row y+1, then prefetch for row y+2
        if (r + 1 < YSW) {
            vs0 += na0 - nu0; vs1 += na1 - nu1; vs2 += na2 - nu2;
            vs3 += na3 - nu3;
            if (hasv4) vs4 += na4 - nu4;
            ct = nt; co = no;

            if (r + 2 < YSW) {
                const int ya = y + 2 + Rn, yu = y + 2 - Rn - 1;
                if ((unsigned)ya < (unsigned)Hn) {
                    const float* rp = tb + (size_t)ya * Wn;
                    na0 = ldc(rp, c0, xok0); na1 = rp[c0 + 64];
                    na2 = rp[c0 + 128];      na3 = rp[c0 + 192];
                    if (hasv4) na4 = ldc(rp, c4, xok4);
                } else { na0 = na1 = na2 = na3 = na4 = 0.f; }
                if ((unsigned)yu < (unsigned)Hn) {
                    const float* rp = tb + (size_t)yu * Wn;
                    nu0 = ldc(rp, c0, xok0); nu1 = rp[c0 + 64];
                    nu2 = rp[c0 + 128];      nu3 = rp[c0 + 192];
                    if (hasv4) nu4 = ldc(rp, c4, xok4);
                } else { nu0 = nu1 = nu2 = nu3 = nu4 = 0.f; }
            }
        }
    }

    // ---- wave reduction + one atomic pair per wave ----
    #pragma unroll
    for (int off = 32; off > 0; off >>= 1) {
        acc_i += __shfl_down(acc_i, off);
        acc_m += __shfl_down(acc_m, off);
    }
    if (t == 0) {
        atomicAdd(&acc[2 * b],     acc_i);
        atomicAdd(&acc[2 * b + 1], acc_m);
    }
}

__global__ void dice_final(const float* __restrict__ acc, float* __restrict__ out)
{
    const int t = threadIdx.x;
    float l = 0.0f;
    if (t < Bn) {
        const float I = acc[2 * t];
        const float M = acc[2 * t + 1];
        l = 1.0f - (2.0f * I + 0.001f) / (M + 0.001f);
    }
    #pragma unroll
    for (int off = 32; off > 0; off >>= 1) l += __shfl_down(l, off);
    if (t == 0) out[0] = l * (1.0f / 32.0f);
}

extern "C" void kernel_launch(void* const* d_in, const int* in_sizes, int n_in,
                              void* d_out, int out_size, void* d_ws, size_t ws_size,
                              hipStream_t stream)
{
    const float* logits = (const float*)d_in[0];   // "output" in reference
    const float* target = (const float*)d_in[1];
    float* acc = (float*)d_ws;                     // 64 floats: (I_b, M_b) per batch

    hipMemsetAsync(d_ws, 0, 64 * sizeof(float), stream);
    dice_main<<<dim3(Bn * 64 / WPB), dim3(256), 0, stream>>>(logits, target, acc);
    dice_final<<<dim3(1), dim3(64), 0, stream>>>(acc, (float*)d_out);
}